// Round 10
// baseline (170.786 us; speedup 1.0000x reference)
//
#include <hip/hip_runtime.h>
#include <hip/hip_bf16.h>
#include <stdint.h>

typedef unsigned short u16;
typedef __bf16 bf16x8 __attribute__((ext_vector_type(8)));
typedef float  f32x4  __attribute__((ext_vector_type(4)));
typedef u16    u16x8  __attribute__((ext_vector_type(8)));
typedef u16    u16x4  __attribute__((ext_vector_type(4)));

// float -> bf16 RNE
__device__ __forceinline__ u16 f2bf(float f) {
  union { float f; unsigned u; } v; v.f = f;
  unsigned u = v.u;
  unsigned r = u + 0x7FFFu + ((u >> 16) & 1u);
  return (u16)(r >> 16);
}

__device__ __forceinline__ void gld_lds16(const void* g, void* l) {
  __builtin_amdgcn_global_load_lds(
      (const __attribute__((address_space(1))) void*)g,
      (__attribute__((address_space(3))) void*)l, 16, 0, 0);
}

// ---- detect int32 vs int64 index storage ----------------------------------
__global__ void detect_idx_width(const unsigned* __restrict__ w, int* __restrict__ flag) {
  unsigned v = w[threadIdx.x * 2 + 1];
  unsigned long long any = __ballot(v != 0u);
  if (threadIdx.x == 0) *flag = (any != 0ull) ? 1 : 0;  // 1 = int32, 0 = int64
}

// ---- x: f32 -> bf16 --------------------------------------------------------
__global__ __launch_bounds__(256) void cvt_x_kernel(const float4* __restrict__ x,
                                                    u16* __restrict__ xb, long n8) {
  long i = (long)blockIdx.x * blockDim.x + threadIdx.x;
  long stride = (long)gridDim.x * blockDim.x;
  for (; i < n8; i += stride) {
    float4 a = x[2 * i];
    float4 b = x[2 * i + 1];
    u16x8 r;
    r[0] = f2bf(a.x); r[1] = f2bf(a.y); r[2] = f2bf(a.z); r[3] = f2bf(a.w);
    r[4] = f2bf(b.x); r[5] = f2bf(b.y); r[6] = f2bf(b.z); r[7] = f2bf(b.w);
    *(u16x8*)(xb + 8 * i) = r;
  }
}

// ---- W: values[w_idx] -> bf16 ---------------------------------------------
__global__ __launch_bounds__(256) void dequant_w_kernel(const int4* __restrict__ widx,
                                                        const float* __restrict__ values,
                                                        u16* __restrict__ wb,
                                                        const int* __restrict__ flag, long n4) {
  const bool is32 = (*flag != 0);
  long i = (long)blockIdx.x * blockDim.x + threadIdx.x;
  long stride = (long)gridDim.x * blockDim.x;
  for (; i < n4; i += stride) {
    int i0, i1, i2, i3;
    if (is32) {
      int4 v = widx[i];
      i0 = v.x; i1 = v.y; i2 = v.z; i3 = v.w;
    } else {
      int4 a = widx[2 * i];
      int4 b = widx[2 * i + 1];
      i0 = a.x; i1 = a.z; i2 = b.x; i3 = b.z;
    }
    u16x4 r;
    r[0] = f2bf(values[i0]); r[1] = f2bf(values[i1]);
    r[2] = f2bf(values[i2]); r[3] = f2bf(values[i3]);
    *(u16x4*)(wb + 4 * i) = r;
  }
}

// ===========================================================================
// 256x256 bf16 GEMM — R10: R9's schedule with ASM s_barrier. The builtin
// s_barrier lets the backend force-drain outstanding LDS-DMA (vmcnt(0)) at
// every phase boundary, defeating the counted-vmcnt ledger (suspected cause
// of the 1220cyc/phase plateau across R4/R6/R8/R9). Inline-asm s_barrier is
// opaque to the waitcnt pass; correctness rests on the explicit VMW ledger
// (re-verified standalone: per-wave VMW retires its region before the
// group-end barrier; all reads occur >=1 barrier later; overwrites trail
// last-reads by >=2 barriers; tails drain VMW(0)).
// A: 2 x 32KB LDS bufs; B: 3 x 32KB (depth-3 staging). 1 group = 1 K-tile.
// ===========================================================================
#define VMW(n) asm volatile("s_waitcnt vmcnt(" #n ")" ::: "memory")
#define PH_BAR asm volatile("s_barrier" ::: "memory")

__global__ __launch_bounds__(512, 1) void gemm256_kernel(
    const u16* __restrict__ Xb, const u16* __restrict__ Wb,
    const float* __restrict__ bias, float* __restrict__ C,
    int Nout, int Kin) {
  __shared__ __align__(16) char lds[163840];  // A:[0,64K) 2 bufs; B:[64K,160K) 3 bufs

  const int tid  = threadIdx.x;
  const int lane = tid & 63;
  const int wave = tid >> 6;
  const int wr = wave >> 2;   // 0..1  (M half)
  const int wc = wave & 3;    // 0..3  (N quarter)

  // bijective XCD swizzle (m204)
  const int nwg = gridDim.x;
  const int bid = blockIdx.x;
  const int q8 = nwg >> 3, r8 = nwg & 7;
  const int xcd = bid & 7;
  const int wg = (xcd < r8 ? xcd * (q8 + 1) : r8 * (q8 + 1) + (xcd - r8) * q8) + (bid >> 3);

  const int tiles_n = Nout / 256;
  const long brow = (long)(wg / tiles_n) * 256;
  const long bcol = (long)(wg % tiles_n) * 256;

  const long rowb = (long)Kin * 2;      // row bytes
  const long rstep = 64 * rowb;         // +64 rows (uniform)
  const long hstep = 128 * rowb;        // +128 rows (uniform)

  // staging: inverse-swizzled global source + linear LDS dest (rule #21)
  const int f0  = tid * 16;
  const int f1  = f0 + 8192;
  const int rS0 = f0 >> 7;        // 0..63
  const int cS  = (f0 & 127) ^ ((rS0 & 7) << 4);
  const int voff = (int)(rS0 * rowb) + cS;   // per-thread, 32-bit

  const char* uA = (const char*)Xb + (size_t)brow * rowb;   // uniform
  const char* uB = (const char*)Wb + (size_t)bcol * rowb;   // uniform

#define STAGE_AH(base_, h, t) { \
  gld_lds16(uA + (size_t)(h) * hstep + (size_t)(t) * 128 + voff,         lds + (base_) + (h) * 16384 + f0); \
  gld_lds16(uA + (size_t)(h) * hstep + (size_t)(t) * 128 + rstep + voff, lds + (base_) + (h) * 16384 + f1); }
#define STAGE_BH(base_, h, t) { \
  gld_lds16(uB + (size_t)(h) * hstep + (size_t)(t) * 128 + voff,         lds + (base_) + (h) * 16384 + f0); \
  gld_lds16(uB + (size_t)(h) * hstep + (size_t)(t) * 128 + rstep + voff, lds + (base_) + (h) * 16384 + f1); }

  // fragment read addressing (swizzled)
  const int fr   = lane & 15;
  const int kb   = (lane >> 4) * 16;
  const int xsw  = (fr & 7) << 4;
  const int colx0 = kb ^ xsw;          // ks = 0
  const int colx1 = (64 + kb) ^ xsw;   // ks = 1
  const int aOff = wr * 16384 + fr * 128;
  const int bOff = (wc >> 1) * 16384 + ((wc & 1) * 64 + fr) * 128;

  bf16x8 afrA[2][2];   // afr ping-pong: q0,q2 -> afrA ; q1,q3 -> afrB
  bf16x8 afrB[2][2];
  bf16x8 bfrE[4][2];   // B-frags, even tiles
  bf16x8 bfrO[4][2];   // B-frags, odd tiles
  f32x4  acc[8][4] = {};

// read A-slice q of tile in abase_ into DST (4 ds_read_b128)
#define READ_AQ(abase_, q, DST) { \
  const char* ab = lds + (abase_) + aOff + (q) * 4096; \
  DST[0][0] = *(const bf16x8*)(ab + colx0); \
  DST[0][1] = *(const bf16x8*)(ab + colx1); \
  DST[1][0] = *(const bf16x8*)(ab + 2048 + colx0); \
  DST[1][1] = *(const bf16x8*)(ab + 2048 + colx1); }

// prefetch 2 of 4 B column-tiles (ni = lo, lo+1) into dst regs
#define READ_BPF(bbase_, dst, lo) { \
  const char* bb = lds + (bbase_) + bOff; \
  dst[(lo)][0]     = *(const bf16x8*)(bb + (lo) * 2048 + colx0); \
  dst[(lo)][1]     = *(const bf16x8*)(bb + (lo) * 2048 + colx1); \
  dst[(lo) + 1][0] = *(const bf16x8*)(bb + ((lo) + 1) * 2048 + colx0); \
  dst[(lo) + 1][1] = *(const bf16x8*)(bb + ((lo) + 1) * 2048 + colx1); }

#define MFMA_Q(q, AF, BF) { \
  __builtin_amdgcn_s_setprio(1); \
  _Pragma("unroll") for (int m2 = 0; m2 < 2; ++m2) \
  _Pragma("unroll") for (int ni = 0; ni < 4; ++ni) { \
    acc[(q)*2+m2][ni] = __builtin_amdgcn_mfma_f32_16x16x32_bf16(AF[m2][0], BF[ni][0], acc[(q)*2+m2][ni], 0, 0, 0); \
    acc[(q)*2+m2][ni] = __builtin_amdgcn_mfma_f32_16x16x32_bf16(AF[m2][1], BF[ni][1], acc[(q)*2+m2][ni], 0, 0, 0); } \
  __builtin_amdgcn_s_setprio(0); }

// phase: reads + stages issued (memory ops pinned by the asm barrier's
// memory clobber), asm barrier (NO implicit waitcnt), MFMA (backend adds
// dependency-driven counted lgkm waits), optional explicit vm wait, barrier.
#define PHASE(RDS, STG, MF, WT) { \
  RDS; STG; PH_BAR; MF; WT; PH_BAR; }

  const int aB0 = 0, aB1 = 32768;
  int bR0 = 65536, bR1 = 98304, bR2 = 131072;  // B(t), B(t+1), B(t+2)
  const int NT = Kin >> 6;

  // prologue: A(0)->aB0, B(0..2); drain; preload bfrE = B(0)
  STAGE_AH(aB0, 0, 0); STAGE_AH(aB0, 1, 0);
  STAGE_BH(bR0, 0, 0); STAGE_BH(bR0, 1, 0);
  if (NT > 1) { STAGE_BH(bR1, 0, 1); STAGE_BH(bR1, 1, 1); }
  if (NT > 2) { STAGE_BH(bR2, 0, 2); STAGE_BH(bR2, 1, 2); }
  VMW(0);
  PH_BAR;
  READ_BPF(bR0, bfrE, 0); READ_BPF(bR0, bfrE, 2);

  const int NITER = NT >> 1;
  // Group g (= K-tile t) ledger: stages ph0:A0(t+1) ph1:A1(t+1) ph2:B0(t+3)
  // ph3:B1(t+3); VMW(4)@ph3-end. Steady: carry {B(t+2)} 4 + issued 8 = 12
  // -> retire 8 = B(t+2) (staged 1 group earlier) + A(t+1) (staged ph0-1),
  // leave {B(t+3)}. All retired regions are first READ >=1 barrier after the
  // VMW (next group), cross-wave safe. Tails (stages skipped): VMW(0).
  for (int i = 0; i < NITER; ++i) {
    const int t0 = i * 2;
    const bool a1 = (t0 + 1 < NT);   // always true in-loop
    const bool a2 = (t0 + 2 < NT);
    const bool b3 = (t0 + 3 < NT);
    const bool b4 = (t0 + 4 < NT);

    // ---- even group t = t0: A in aB0, consume bfrE, prefetch bfrO (bR1)
    PHASE({ READ_AQ(aB0, 0, afrA); READ_AQ(aB0, 1, afrB); },
          { if (a1) STAGE_AH(aB1, 0, t0 + 1); },
          MFMA_Q(0, afrA, bfrE), (void)0);
    PHASE({ READ_AQ(aB0, 2, afrA); if (a1) READ_BPF(bR1, bfrO, 0); },
          { if (a1) STAGE_AH(aB1, 1, t0 + 1); },
          MFMA_Q(1, afrB, bfrE), (void)0);
    PHASE({ READ_AQ(aB0, 3, afrB); if (a1) READ_BPF(bR1, bfrO, 2); },
          { if (b3) STAGE_BH(bR0, 0, t0 + 3); },
          MFMA_Q(2, afrA, bfrE), (void)0);
    PHASE({ (void)0; },
          { if (b3) STAGE_BH(bR0, 1, t0 + 3); },
          MFMA_Q(3, afrB, bfrE),
          { if (b3) { VMW(4); } else { VMW(0); } });

    // ---- odd group t = t0+1: A in aB1, consume bfrO, prefetch bfrE (bR2)
    PHASE({ READ_AQ(aB1, 0, afrA); READ_AQ(aB1, 1, afrB); },
          { if (a2) STAGE_AH(aB0, 0, t0 + 2); },
          MFMA_Q(0, afrA, bfrO), (void)0);
    PHASE({ READ_AQ(aB1, 2, afrA); if (a2) READ_BPF(bR2, bfrE, 0); },
          { if (a2) STAGE_AH(aB0, 1, t0 + 2); },
          MFMA_Q(1, afrB, bfrO), (void)0);
    PHASE({ READ_AQ(aB1, 3, afrB); if (a2) READ_BPF(bR2, bfrE, 2); },
          { if (b4) STAGE_BH(bR1, 0, t0 + 4); },
          MFMA_Q(2, afrA, bfrO), (void)0);
    PHASE({ (void)0; },
          { if (b4) STAGE_BH(bR1, 1, t0 + 4); },
          MFMA_Q(3, afrB, bfrO),
          { if (b4) { VMW(4); } else { VMW(0); } });

    // rotate B bufs: (bR0,bR1,bR2) <- (bR2,bR0,bR1)
    int tmp = bR0; bR0 = bR2; bR2 = bR1; bR1 = tmp;
  }

  // epilogue: C/D layout col = lane&15, row = (lane>>4)*4 + j
  const int cm = (lane >> 4) * 4;
  const int cn = lane & 15;
  float bv[4];
#pragma unroll
  for (int ni = 0; ni < 4; ++ni) bv[ni] = bias[bcol + wc * 64 + ni * 16 + cn];

#pragma unroll
  for (int mi = 0; mi < 8; ++mi) {
    const long row0 = brow + wr * 128 + mi * 16 + cm;
#pragma unroll
    for (int ni = 0; ni < 4; ++ni) {
      const long col = bcol + wc * 64 + ni * 16 + cn;
#pragma unroll
      for (int j = 0; j < 4; ++j)
        C[(row0 + j) * (long)Nout + col] = acc[mi][ni][j] + bv[ni];
    }
  }
#undef STAGE_AH
#undef STAGE_BH
#undef READ_AQ
#undef READ_BPF
#undef MFMA_Q
#undef PHASE
}

// ---- 128x128 m97-structure fallback (verified in R1) -----------------------
__global__ __launch_bounds__(256, 2) void gemm128_kernel(
    const u16* __restrict__ Xb, const u16* __restrict__ Wb,
    const float* __restrict__ bias, float* __restrict__ C,
    int Nout, int Kin) {
  __shared__ __align__(16) u16 As[128 * 32];
  __shared__ __align__(16) u16 Bs[128 * 32];
  const int tid  = threadIdx.x;
  const int lane = tid & 63;
  const int wave = tid >> 6;
  const int wr = wave >> 1, wc = wave & 1;
  const int nwg = gridDim.x, bid = blockIdx.x;
  const int q = nwg >> 3, r8 = nwg & 7;
  const int xcd = bid & 7;
  const int wg = (xcd < r8 ? xcd * (q + 1) : r8 * (q + 1) + (xcd - r8) * q) + (bid >> 3);
  const int tiles_n = Nout / 128;
  const long brow = (long)(wg / tiles_n) * 128;
  const long bcol = (long)(wg % tiles_n) * 128;
  const int f0 = tid * 16, f1 = f0 + 4096;
  const size_t rowbytes = (size_t)Kin * 2;
  const char* gA0 = (const char*)Xb + (size_t)(brow + (f0 >> 6)) * rowbytes + (f0 & 63);
  const char* gA1 = (const char*)Xb + (size_t)(brow + (f1 >> 6)) * rowbytes + (f1 & 63);
  const char* gB0 = (const char*)Wb + (size_t)(bcol + (f0 >> 6)) * rowbytes + (f0 & 63);
  const char* gB1 = (const char*)Wb + (size_t)(bcol + (f1 >> 6)) * rowbytes + (f1 & 63);
  char* lA0 = (char*)As + f0; char* lA1 = (char*)As + f1;
  char* lB0 = (char*)Bs + f0; char* lB1 = (char*)Bs + f1;
  const int fr = lane & 15, kb = (lane >> 4) * 16;
  const char* aptr[4]; const char* bptr[4];
#pragma unroll
  for (int i = 0; i < 4; ++i) {
    aptr[i] = (const char*)As + (wr * 64 + i * 16 + fr) * 64 + kb;
    bptr[i] = (const char*)Bs + (wc * 64 + i * 16 + fr) * 64 + kb;
  }
  f32x4 acc[4][4] = {};
  for (int kk = 0; kk < Kin; kk += 32) {
    const size_t ko = (size_t)kk * 2;
    gld_lds16(gA0 + ko, lA0); gld_lds16(gA1 + ko, lA1);
    gld_lds16(gB0 + ko, lB0); gld_lds16(gB1 + ko, lB1);
    __syncthreads();
    bf16x8 a[4], b[4];
#pragma unroll
    for (int i = 0; i < 4; ++i) a[i] = *(const bf16x8*)aptr[i];
#pragma unroll
    for (int i = 0; i < 4; ++i) b[i] = *(const bf16x8*)bptr[i];
#pragma unroll
    for (int mi = 0; mi < 4; ++mi)
#pragma unroll
      for (int ni = 0; ni < 4; ++ni)
        acc[mi][ni] = __builtin_amdgcn_mfma_f32_16x16x32_bf16(a[mi], b[ni], acc[mi][ni], 0, 0, 0);
    __syncthreads();
  }
  const int cm = (lane >> 4) * 4, cn = lane & 15;
  float bv[4];
#pragma unroll
  for (int ni = 0; ni < 4; ++ni) bv[ni] = bias[bcol + wc * 64 + ni * 16 + cn];
#pragma unroll
  for (int mi = 0; mi < 4; ++mi) {
    const long row0 = brow + wr * 64 + mi * 16 + cm;
#pragma unroll
    for (int ni = 0; ni < 4; ++ni) {
      const long col = bcol + wc * 64 + ni * 16 + cn;
#pragma unroll
      for (int j = 0; j < 4; ++j)
        C[(row0 + j) * (long)Nout + col] = acc[mi][ni][j] + bv[ni];
    }
  }
}

// ---- naive fallback --------------------------------------------------------
__global__ void fallback_kernel(const float* __restrict__ x, const float* __restrict__ values,
                                const int* __restrict__ widx, const float* __restrict__ bias,
                                float* __restrict__ out, const int* __restrict__ flag,
                                int NT, int IF, int OF) {
  const int o = blockIdx.x * blockDim.x + threadIdx.x;
  const int t = blockIdx.y;
  if (o >= OF || t >= NT) return;
  const bool is32 = (*flag != 0);
  const float* xr = x + (size_t)t * IF;
  float sum = 0.f;
  if (is32) {
    const int* w = widx + (size_t)o * IF;
    for (int k = 0; k < IF; ++k) sum += xr[k] * values[w[k]];
  } else {
    const long long* w = (const long long*)widx + (size_t)o * IF;
    for (int k = 0; k < IF; ++k) sum += xr[k] * values[(int)w[k]];
  }
  out[(size_t)t * OF + o] = sum + bias[o];
}

extern "C" void kernel_launch(void* const* d_in, const int* in_sizes, int n_in,
                              void* d_out, int out_size, void* d_ws, size_t ws_size,
                              hipStream_t stream) {
  const float* x      = (const float*)d_in[0];
  const float* values = (const float*)d_in[1];
  const int*   widx   = (const int*)d_in[2];
  const float* bias   = (const float*)d_in[3];
  float* out = (float*)d_out;

  const long xsz = in_sizes[0];
  const int  OF  = in_sizes[3];
  const long wsz = in_sizes[2];
  const int  IF  = (int)(wsz / OF);
  const int  NTOK = (int)(xsz / IF);

  u16* xb = (u16*)d_ws;
  u16* wb = xb + (size_t)NTOK * IF;
  int* flag = (int*)(wb + (size_t)OF * IF);
  const size_t need = ((size_t)NTOK * IF + (size_t)OF * IF) * sizeof(u16) + 64;

  const bool pre_ok = (ws_size >= need) && ((xsz % 8) == 0) && ((wsz % 4) == 0);
  const bool f256 = pre_ok && (IF % 128 == 0) && (IF >= 256) &&
                    (NTOK % 256 == 0) && (OF % 256 == 0);
  const bool f128 = pre_ok && (IF % 32 == 0) && (NTOK % 128 == 0) && (OF % 128 == 0);

  if (f256 || f128) {
    hipLaunchKernelGGL(detect_idx_width, dim3(1), dim3(64), 0, stream,
                       (const unsigned*)widx, flag);
    hipLaunchKernelGGL(cvt_x_kernel, dim3(2048), dim3(256), 0, stream,
                       (const float4*)x, xb, xsz / 8);
    hipLaunchKernelGGL(dequant_w_kernel, dim3(2048), dim3(256), 0, stream,
                       (const int4*)widx, values, wb, (const int*)flag, wsz / 4);
    if (f256) {
      const int grid = (NTOK / 256) * (OF / 256);
      hipLaunchKernelGGL(gemm256_kernel, dim3(grid), dim3(512), 0, stream,
                         xb, wb, bias, out, OF, IF);
    } else {
      const int grid = (NTOK / 128) * (OF / 128);
      hipLaunchKernelGGL(gemm128_kernel, dim3(grid), dim3(256), 0, stream,
                         xb, wb, bias, out, OF, IF);
    }
  } else {
    int* flag2 = (int*)d_ws;
    hipLaunchKernelGGL(detect_idx_width, dim3(1), dim3(64), 0, stream,
                       (const unsigned*)widx, flag2);
    hipLaunchKernelGGL(fallback_kernel, dim3((OF + 255) / 256, NTOK), dim3(256), 0, stream,
                       x, values, widx, bias, out, (const int*)flag2, NTOK, IF, OF);
  }
}

// Round 11
// 154.567 us; speedup vs baseline: 1.1049x; 1.1049x over previous
//
#include <hip/hip_runtime.h>
#include <hip/hip_bf16.h>
#include <stdint.h>

typedef unsigned short u16;
typedef __bf16 bf16x8 __attribute__((ext_vector_type(8)));
typedef float  f32x4  __attribute__((ext_vector_type(4)));
typedef u16    u16x8  __attribute__((ext_vector_type(8)));
typedef u16    u16x4  __attribute__((ext_vector_type(4)));

// float -> bf16 RNE
__device__ __forceinline__ u16 f2bf(float f) {
  union { float f; unsigned u; } v; v.f = f;
  unsigned u = v.u;
  unsigned r = u + 0x7FFFu + ((u >> 16) & 1u);
  return (u16)(r >> 16);
}

__device__ __forceinline__ void gld_lds16(const void* g, void* l) {
  __builtin_amdgcn_global_load_lds(
      (const __attribute__((address_space(1))) void*)g,
      (__attribute__((address_space(3))) void*)l, 16, 0, 0);
}

// ---- detect int32 vs int64 index storage ----------------------------------
__global__ void detect_idx_width(const unsigned* __restrict__ w, int* __restrict__ flag) {
  unsigned v = w[threadIdx.x * 2 + 1];
  unsigned long long any = __ballot(v != 0u);
  if (threadIdx.x == 0) *flag = (any != 0ull) ? 1 : 0;  // 1 = int32, 0 = int64
}

// ---- fused prepass: x f32->bf16 AND W dequant (independent ranges) ---------
__global__ __launch_bounds__(256) void prepass_kernel(
    const float4* __restrict__ x, u16* __restrict__ xb, long n8,
    const int4* __restrict__ widx, const float* __restrict__ values,
    u16* __restrict__ wb, const int* __restrict__ flag, long n4) {
  const long gid = (long)blockIdx.x * blockDim.x + threadIdx.x;
  const long stride = (long)gridDim.x * blockDim.x;
  for (long i = gid; i < n8; i += stride) {
    float4 a = x[2 * i];
    float4 b = x[2 * i + 1];
    u16x8 r;
    r[0] = f2bf(a.x); r[1] = f2bf(a.y); r[2] = f2bf(a.z); r[3] = f2bf(a.w);
    r[4] = f2bf(b.x); r[5] = f2bf(b.y); r[6] = f2bf(b.z); r[7] = f2bf(b.w);
    *(u16x8*)(xb + 8 * i) = r;
  }
  const bool is32 = (*flag != 0);
  for (long i = gid; i < n4; i += stride) {
    int i0, i1, i2, i3;
    if (is32) {
      int4 v = widx[i];
      i0 = v.x; i1 = v.y; i2 = v.z; i3 = v.w;
    } else {
      int4 a = widx[2 * i];
      int4 b = widx[2 * i + 1];
      i0 = a.x; i1 = a.z; i2 = b.x; i3 = b.z;
    }
    u16x4 r;
    r[0] = f2bf(values[i0]); r[1] = f2bf(values[i1]);
    r[2] = f2bf(values[i2]); r[3] = f2bf(values[i3]);
    *(u16x4*)(wb + 4 * i) = r;
  }
}

// ===========================================================================
// 256x256 bf16 GEMM — R11: MFMA<->ds_read ISSUE interleave (T19) on R8's
// ledger. Diagnosis: per K-tile LDS work (2304cyc) + MFMA work (2484cyc)
// sum to the measured 4880cyc — pipes never overlap because read-blocks
// stall on the LDS request queue at issue time BEFORE each MFMA-block.
// Fix: weave 1 memory op between every 2 MFMAs via sched_group_barrier
// (reads consumed one phase later -> no intra-phase dependency). One
// barrier per phase; main loop guard-free (single scheduling region);
// guarded tail iterations drain with vmcnt(0).
// A: 2 x 32KB LDS bufs; B: 3 x 32KB. VMW(2) at ph2-end (R5 ledger:
// outstanding 10 -> retires B(t+2)+A(t+1), keeps B0(t+3); ph3's cross-tile
// afr(q0,t+1) read sits after {VMW, barrier}).
// ===========================================================================
#define VMW(n) asm volatile("s_waitcnt vmcnt(" #n ")" ::: "memory")
#define PH_BAR asm volatile("s_barrier" ::: "memory")
#define SGB(m, n) __builtin_amdgcn_sched_group_barrier((m), (n), 0)
#define NOWT (void)0

__global__ __launch_bounds__(512, 1) void gemm256_kernel(
    const u16* __restrict__ Xb, const u16* __restrict__ Wb,
    const float* __restrict__ bias, float* __restrict__ C,
    int Nout, int Kin) {
  __shared__ __align__(16) char lds[163840];  // A:[0,64K) 2 bufs; B:[64K,160K) 3 bufs

  const int tid  = threadIdx.x;
  const int lane = tid & 63;
  const int wave = tid >> 6;
  const int wr = wave >> 2;   // 0..1  (M half)
  const int wc = wave & 3;    // 0..3  (N quarter)

  // bijective XCD swizzle (m204)
  const int nwg = gridDim.x;
  const int bid = blockIdx.x;
  const int q8 = nwg >> 3, r8 = nwg & 7;
  const int xcd = bid & 7;
  const int wg = (xcd < r8 ? xcd * (q8 + 1) : r8 * (q8 + 1) + (xcd - r8) * q8) + (bid >> 3);

  const int tiles_n = Nout / 256;
  const long brow = (long)(wg / tiles_n) * 256;
  const long bcol = (long)(wg % tiles_n) * 256;

  const long rowb  = (long)Kin * 2;     // row bytes
  const long rstep = 64 * rowb;         // +64 rows (uniform)
  const long hstep = 128 * rowb;        // +128 rows (uniform)

  // staging: inverse-swizzled global source + linear LDS dest (rule #21)
  const int f0  = tid * 16;
  const int f1  = f0 + 8192;
  const int rS0 = f0 >> 7;
  const int cS  = (f0 & 127) ^ ((rS0 & 7) << 4);
  const int voff = (int)(rS0 * rowb) + cS;

  const char* uA = (const char*)Xb + (size_t)brow * rowb;
  const char* uB = (const char*)Wb + (size_t)bcol * rowb;

// single gld_lds (half of a half-tile stage); part=0 -> rows 0-63, 1 -> 64-127
#define SA1(base_, h, t, part) \
  gld_lds16(uA + (size_t)(h) * hstep + (size_t)(t) * 128 + ((part) ? rstep : 0) + voff, \
            lds + (base_) + (h) * 16384 + ((part) ? f1 : f0));
#define SB1(base_, h, t, part) \
  gld_lds16(uB + (size_t)(h) * hstep + (size_t)(t) * 128 + ((part) ? rstep : 0) + voff, \
            lds + (base_) + (h) * 16384 + ((part) ? f1 : f0));

  // fragment read addressing (swizzled)
  const int fr   = lane & 15;
  const int kb   = (lane >> 4) * 16;
  const int xsw  = (fr & 7) << 4;
  const int colx0 = kb ^ xsw;
  const int colx1 = (64 + kb) ^ xsw;
  const int aOff = wr * 16384 + fr * 128;
  const int bOff = (wc >> 1) * 16384 + ((wc & 1) * 64 + fr) * 128;

  bf16x8 afrA[2][2];   // MFMA(q) consumes afrA if q even, afrB if q odd
  bf16x8 afrB[2][2];
  bf16x8 bfrE[4][2];   // B-frags, even tiles
  bf16x8 bfrO[4][2];   // B-frags, odd tiles
  f32x4  acc[8][4] = {};

// single ds_read_b128: A-slice q, sub m2, k-slot ks
#define RDA(abase_, q, DST, m2, ks) \
  DST[(m2)][(ks)] = *(const bf16x8*)(lds + (abase_) + aOff + (q) * 4096 + (m2) * 2048 + ((ks) ? colx1 : colx0));
// single ds_read_b128: B column-tile ni, k-slot ks
#define RDB(bbase_, DST, ni, ks) \
  DST[(ni)][(ks)] = *(const bf16x8*)(lds + (bbase_) + bOff + (ni) * 2048 + ((ks) ? colx1 : colx0));

#define MFMA1(d, a, b) d = __builtin_amdgcn_mfma_f32_16x16x32_bf16((a), (b), (d), 0, 0, 0)
#define MM2(q, m2, ni, AF, BF) { \
  MFMA1(acc[(q)*2+(m2)][(ni)], AF[(m2)][0], BF[(ni)][0]); \
  MFMA1(acc[(q)*2+(m2)][(ni)], AF[(m2)][1], BF[(ni)][1]); }

// Phase: 16 MFMA interleaved 2:1 with 6 ds_reads + 2 gld_lds (T19 pattern).
// All reads feed the NEXT phase; stages are ledger-placed; WT = counted vmcnt.
#define PHASE(q, AF, BF, R0, R1, R2, R3, R4, R5, S0, S1, WT) { \
  MM2(q, 0, 0, AF, BF); SGB(0x8, 2); R0; SGB(0x100, 1); \
  MM2(q, 1, 0, AF, BF); SGB(0x8, 2); R1; SGB(0x100, 1); \
  MM2(q, 0, 1, AF, BF); SGB(0x8, 2); R2; SGB(0x100, 1); \
  MM2(q, 1, 1, AF, BF); SGB(0x8, 2); R3; SGB(0x100, 1); \
  MM2(q, 0, 2, AF, BF); SGB(0x8, 2); R4; SGB(0x100, 1); \
  MM2(q, 1, 2, AF, BF); SGB(0x8, 2); R5; SGB(0x100, 1); \
  MM2(q, 0, 3, AF, BF); SGB(0x8, 2); S0; SGB(0x70, 1); \
  MM2(q, 1, 3, AF, BF); SGB(0x8, 2); S1; SGB(0x70, 1); \
  WT; PH_BAR; }

  const int aB0 = 0, aB1 = 32768;
  int bR0 = 65536, bR1 = 98304, bR2 = 131072;  // B(t), B(t+1), B(t+2)
  const int NT = Kin >> 6;

  // prologue: A(0)->aB0, B(0..2); drain; preload bfrE=B(0), afrA=A(0,q0)
  SA1(aB0, 0, 0, 0); SA1(aB0, 0, 0, 1); SA1(aB0, 1, 0, 0); SA1(aB0, 1, 0, 1);
  SB1(bR0, 0, 0, 0); SB1(bR0, 0, 0, 1); SB1(bR0, 1, 0, 0); SB1(bR0, 1, 0, 1);
  SB1(bR1, 0, 1, 0); SB1(bR1, 0, 1, 1); SB1(bR1, 1, 1, 0); SB1(bR1, 1, 1, 1);
  SB1(bR2, 0, 2, 0); SB1(bR2, 0, 2, 1); SB1(bR2, 1, 2, 0); SB1(bR2, 1, 2, 1);
  VMW(0);
  PH_BAR;
  RDB(bR0, bfrE, 0, 0); RDB(bR0, bfrE, 0, 1); RDB(bR0, bfrE, 1, 0); RDB(bR0, bfrE, 1, 1);
  RDB(bR0, bfrE, 2, 0); RDB(bR0, bfrE, 2, 1); RDB(bR0, bfrE, 3, 0); RDB(bR0, bfrE, 3, 1);
  RDA(aB0, 0, afrA, 0, 0); RDA(aB0, 0, afrA, 0, 1); RDA(aB0, 0, afrA, 1, 0); RDA(aB0, 0, afrA, 1, 1);

  // ---- main loop: unconditional stages (requires t0+4 < NT) ----
  // Group t ledger: ph0 A0(t+1), ph1 A1(t+1), ph2 B0(t+3)+VMW(2), ph3 B1(t+3).
  // @ph2-end: carry{B(t+2)}4 + A(t+1)4 + B0(t+3)2 = 10 -> keep 2 = B0(t+3);
  // retires B(t+2) (read next tile) and A(t+1) (cross-read at ph3, after the
  // ph2-end barrier). Reads per phase: 4 afr(q+1) + 2 bfr(next tile).
  const int NITER = NT >> 1;
  const int MAIN = NITER - 2;
  for (int i = 0; i < MAIN; ++i) {
    const int t0 = i * 2;
    // even tile t0: A in aB0, consume bfrE, prefetch bfrO (from bR1)
    PHASE(0, afrA, bfrE,
          RDA(aB0, 1, afrB, 0, 0), RDA(aB0, 1, afrB, 0, 1), RDA(aB0, 1, afrB, 1, 0), RDA(aB0, 1, afrB, 1, 1),
          RDB(bR1, bfrO, 0, 0), RDB(bR1, bfrO, 0, 1),
          SA1(aB1, 0, t0 + 1, 0), SA1(aB1, 0, t0 + 1, 1), NOWT);
    PHASE(1, afrB, bfrE,
          RDA(aB0, 2, afrA, 0, 0), RDA(aB0, 2, afrA, 0, 1), RDA(aB0, 2, afrA, 1, 0), RDA(aB0, 2, afrA, 1, 1),
          RDB(bR1, bfrO, 1, 0), RDB(bR1, bfrO, 1, 1),
          SA1(aB1, 1, t0 + 1, 0), SA1(aB1, 1, t0 + 1, 1), NOWT);
    PHASE(2, afrA, bfrE,
          RDA(aB0, 3, afrB, 0, 0), RDA(aB0, 3, afrB, 0, 1), RDA(aB0, 3, afrB, 1, 0), RDA(aB0, 3, afrB, 1, 1),
          RDB(bR1, bfrO, 2, 0), RDB(bR1, bfrO, 2, 1),
          SB1(bR0, 0, t0 + 3, 0), SB1(bR0, 0, t0 + 3, 1), VMW(2));
    PHASE(3, afrB, bfrE,
          RDA(aB1, 0, afrA, 0, 0), RDA(aB1, 0, afrA, 0, 1), RDA(aB1, 0, afrA, 1, 0), RDA(aB1, 0, afrA, 1, 1),
          RDB(bR1, bfrO, 3, 0), RDB(bR1, bfrO, 3, 1),
          SB1(bR0, 1, t0 + 3, 0), SB1(bR0, 1, t0 + 3, 1), NOWT);
    // odd tile t0+1: A in aB1, consume bfrO, prefetch bfrE (from bR2)
    PHASE(0, afrA, bfrO,
          RDA(aB1, 1, afrB, 0, 0), RDA(aB1, 1, afrB, 0, 1), RDA(aB1, 1, afrB, 1, 0), RDA(aB1, 1, afrB, 1, 1),
          RDB(bR2, bfrE, 0, 0), RDB(bR2, bfrE, 0, 1),
          SA1(aB0, 0, t0 + 2, 0), SA1(aB0, 0, t0 + 2, 1), NOWT);
    PHASE(1, afrB, bfrO,
          RDA(aB1, 2, afrA, 0, 0), RDA(aB1, 2, afrA, 0, 1), RDA(aB1, 2, afrA, 1, 0), RDA(aB1, 2, afrA, 1, 1),
          RDB(bR2, bfrE, 1, 0), RDB(bR2, bfrE, 1, 1),
          SA1(aB0, 1, t0 + 2, 0), SA1(aB0, 1, t0 + 2, 1), NOWT);
    PHASE(2, afrA, bfrO,
          RDA(aB1, 3, afrB, 0, 0), RDA(aB1, 3, afrB, 0, 1), RDA(aB1, 3, afrB, 1, 0), RDA(aB1, 3, afrB, 1, 1),
          RDB(bR2, bfrE, 2, 0), RDB(bR2, bfrE, 2, 1),
          SB1(bR1, 0, t0 + 4, 0), SB1(bR1, 0, t0 + 4, 1), VMW(2));
    PHASE(3, afrB, bfrO,
          RDA(aB0, 0, afrA, 0, 0), RDA(aB0, 0, afrA, 0, 1), RDA(aB0, 0, afrA, 1, 0), RDA(aB0, 0, afrA, 1, 1),
          RDB(bR2, bfrE, 3, 0), RDB(bR2, bfrE, 3, 1),
          SB1(bR1, 1, t0 + 4, 0), SB1(bR1, 1, t0 + 4, 1), NOWT);
    int tmp = bR0; bR0 = bR2; bR2 = bR1; bR1 = tmp;
  }

  // ---- tail: last 2 iterations (4 tiles) with guarded stages, VMW(0) ----
  for (int i = (MAIN > 0 ? MAIN : 0); i < NITER; ++i) {
    const int t0 = i * 2;
    const bool a1 = (t0 + 1 < NT);
    const bool a2 = (t0 + 2 < NT);
    const bool b3 = (t0 + 3 < NT);
    const bool b4 = (t0 + 4 < NT);
    PHASE(0, afrA, bfrE,
          RDA(aB0, 1, afrB, 0, 0), RDA(aB0, 1, afrB, 0, 1), RDA(aB0, 1, afrB, 1, 0), RDA(aB0, 1, afrB, 1, 1),
          RDB(bR1, bfrO, 0, 0), RDB(bR1, bfrO, 0, 1),
          { if (a1) SA1(aB1, 0, t0 + 1, 0) }, { if (a1) SA1(aB1, 0, t0 + 1, 1) }, NOWT);
    PHASE(1, afrB, bfrE,
          RDA(aB0, 2, afrA, 0, 0), RDA(aB0, 2, afrA, 0, 1), RDA(aB0, 2, afrA, 1, 0), RDA(aB0, 2, afrA, 1, 1),
          RDB(bR1, bfrO, 1, 0), RDB(bR1, bfrO, 1, 1),
          { if (a1) SA1(aB1, 1, t0 + 1, 0) }, { if (a1) SA1(aB1, 1, t0 + 1, 1) }, NOWT);
    PHASE(2, afrA, bfrE,
          RDA(aB0, 3, afrB, 0, 0), RDA(aB0, 3, afrB, 0, 1), RDA(aB0, 3, afrB, 1, 0), RDA(aB0, 3, afrB, 1, 1),
          RDB(bR1, bfrO, 2, 0), RDB(bR1, bfrO, 2, 1),
          { if (b3) SB1(bR0, 0, t0 + 3, 0) }, { if (b3) SB1(bR0, 0, t0 + 3, 1) }, VMW(0));
    PHASE(3, afrB, bfrE,
          RDA(aB1, 0, afrA, 0, 0), RDA(aB1, 0, afrA, 0, 1), RDA(aB1, 0, afrA, 1, 0), RDA(aB1, 0, afrA, 1, 1),
          RDB(bR1, bfrO, 3, 0), RDB(bR1, bfrO, 3, 1),
          { if (b3) SB1(bR0, 1, t0 + 3, 0) }, { if (b3) SB1(bR0, 1, t0 + 3, 1) }, NOWT);
    PHASE(0, afrA, bfrO,
          RDA(aB1, 1, afrB, 0, 0), RDA(aB1, 1, afrB, 0, 1), RDA(aB1, 1, afrB, 1, 0), RDA(aB1, 1, afrB, 1, 1),
          RDB(bR2, bfrE, 0, 0), RDB(bR2, bfrE, 0, 1),
          { if (a2) SA1(aB0, 0, t0 + 2, 0) }, { if (a2) SA1(aB0, 0, t0 + 2, 1) }, NOWT);
    PHASE(1, afrB, bfrO,
          RDA(aB1, 2, afrA, 0, 0), RDA(aB1, 2, afrA, 0, 1), RDA(aB1, 2, afrA, 1, 0), RDA(aB1, 2, afrA, 1, 1),
          RDB(bR2, bfrE, 1, 0), RDB(bR2, bfrE, 1, 1),
          { if (a2) SA1(aB0, 1, t0 + 2, 0) }, { if (a2) SA1(aB0, 1, t0 + 2, 1) }, NOWT);
    PHASE(2, afrA, bfrO,
          RDA(aB1, 3, afrB, 0, 0), RDA(aB1, 3, afrB, 0, 1), RDA(aB1, 3, afrB, 1, 0), RDA(aB1, 3, afrB, 1, 1),
          RDB(bR2, bfrE, 2, 0), RDB(bR2, bfrE, 2, 1),
          { if (b4) SB1(bR1, 0, t0 + 4, 0) }, { if (b4) SB1(bR1, 0, t0 + 4, 1) }, VMW(0));
    PHASE(3, afrB, bfrO,
          RDA(aB0, 0, afrA, 0, 0), RDA(aB0, 0, afrA, 0, 1), RDA(aB0, 0, afrA, 1, 0), RDA(aB0, 0, afrA, 1, 1),
          RDB(bR2, bfrE, 3, 0), RDB(bR2, bfrE, 3, 1),
          { if (b4) SB1(bR1, 1, t0 + 4, 0) }, { if (b4) SB1(bR1, 1, t0 + 4, 1) }, NOWT);
    int tmp = bR0; bR0 = bR2; bR2 = bR1; bR1 = tmp;
  }

  // epilogue: C/D layout col = lane&15, row = (lane>>4)*4 + j
  const int cm = (lane >> 4) * 4;
  const int cn = lane & 15;
  float bv[4];
#pragma unroll
  for (int ni = 0; ni < 4; ++ni) bv[ni] = bias[bcol + wc * 64 + ni * 16 + cn];

#pragma unroll
  for (int mi = 0; mi < 8; ++mi) {
    const long row0 = brow + wr * 128 + mi * 16 + cm;
#pragma unroll
    for (int ni = 0; ni < 4; ++ni) {
      const long col = bcol + wc * 64 + ni * 16 + cn;
#pragma unroll
      for (int j = 0; j < 4; ++j)
        C[(row0 + j) * (long)Nout + col] = acc[mi][ni][j] + bv[ni];
    }
  }
#undef SA1
#undef SB1
#undef RDA
#undef RDB
#undef MFMA1
#undef MM2
#undef PHASE
}

// ---- 128x128 m97-structure fallback (verified in R1) -----------------------
__global__ __launch_bounds__(256, 2) void gemm128_kernel(
    const u16* __restrict__ Xb, const u16* __restrict__ Wb,
    const float* __restrict__ bias, float* __restrict__ C,
    int Nout, int Kin) {
  __shared__ __align__(16) u16 As[128 * 32];
  __shared__ __align__(16) u16 Bs[128 * 32];
  const int tid  = threadIdx.x;
  const int lane = tid & 63;
  const int wave = tid >> 6;
  const int wr = wave >> 1, wc = wave & 1;
  const int nwg = gridDim.x, bid = blockIdx.x;
  const int q = nwg >> 3, r8 = nwg & 7;
  const int xcd = bid & 7;
  const int wg = (xcd < r8 ? xcd * (q + 1) : r8 * (q + 1) + (xcd - r8) * q) + (bid >> 3);
  const int tiles_n = Nout / 128;
  const long brow = (long)(wg / tiles_n) * 128;
  const long bcol = (long)(wg % tiles_n) * 128;
  const int f0 = tid * 16, f1 = f0 + 4096;
  const size_t rowbytes = (size_t)Kin * 2;
  const char* gA0 = (const char*)Xb + (size_t)(brow + (f0 >> 6)) * rowbytes + (f0 & 63);
  const char* gA1 = (const char*)Xb + (size_t)(brow + (f1 >> 6)) * rowbytes + (f1 & 63);
  const char* gB0 = (const char*)Wb + (size_t)(bcol + (f0 >> 6)) * rowbytes + (f0 & 63);
  const char* gB1 = (const char*)Wb + (size_t)(bcol + (f1 >> 6)) * rowbytes + (f1 & 63);
  char* lA0 = (char*)As + f0; char* lA1 = (char*)As + f1;
  char* lB0 = (char*)Bs + f0; char* lB1 = (char*)Bs + f1;
  const int fr = lane & 15, kb = (lane >> 4) * 16;
  const char* aptr[4]; const char* bptr[4];
#pragma unroll
  for (int i = 0; i < 4; ++i) {
    aptr[i] = (const char*)As + (wr * 64 + i * 16 + fr) * 64 + kb;
    bptr[i] = (const char*)Bs + (wc * 64 + i * 16 + fr) * 64 + kb;
  }
  f32x4 acc[4][4] = {};
  for (int kk = 0; kk < Kin; kk += 32) {
    const size_t ko = (size_t)kk * 2;
    gld_lds16(gA0 + ko, lA0); gld_lds16(gA1 + ko, lA1);
    gld_lds16(gB0 + ko, lB0); gld_lds16(gB1 + ko, lB1);
    __syncthreads();
    bf16x8 a[4], b[4];
#pragma unroll
    for (int i = 0; i < 4; ++i) a[i] = *(const bf16x8*)aptr[i];
#pragma unroll
    for (int i = 0; i < 4; ++i) b[i] = *(const bf16x8*)bptr[i];
#pragma unroll
    for (int mi = 0; mi < 4; ++mi)
#pragma unroll
      for (int ni = 0; ni < 4; ++ni)
        acc[mi][ni] = __builtin_amdgcn_mfma_f32_16x16x32_bf16(a[mi], b[ni], acc[mi][ni], 0, 0, 0);
    __syncthreads();
  }
  const int cm = (lane >> 4) * 4, cn = lane & 15;
  float bv[4];
#pragma unroll
  for (int ni = 0; ni < 4; ++ni) bv[ni] = bias[bcol + wc * 64 + ni * 16 + cn];
#pragma unroll
  for (int mi = 0; mi < 4; ++mi) {
    const long row0 = brow + wr * 64 + mi * 16 + cm;
#pragma unroll
    for (int ni = 0; ni < 4; ++ni) {
      const long col = bcol + wc * 64 + ni * 16 + cn;
#pragma unroll
      for (int j = 0; j < 4; ++j)
        C[(row0 + j) * (long)Nout + col] = acc[mi][ni][j] + bv[ni];
    }
  }
}

// ---- naive fallback --------------------------------------------------------
__global__ void fallback_kernel(const float* __restrict__ x, const float* __restrict__ values,
                                const int* __restrict__ widx, const float* __restrict__ bias,
                                float* __restrict__ out, const int* __restrict__ flag,
                                int NT, int IF, int OF) {
  const int o = blockIdx.x * blockDim.x + threadIdx.x;
  const int t = blockIdx.y;
  if (o >= OF || t >= NT) return;
  const bool is32 = (*flag != 0);
  const float* xr = x + (size_t)t * IF;
  float sum = 0.f;
  if (is32) {
    const int* w = widx + (size_t)o * IF;
    for (int k = 0; k < IF; ++k) sum += xr[k] * values[w[k]];
  } else {
    const long long* w = (const long long*)widx + (size_t)o * IF;
    for (int k = 0; k < IF; ++k) sum += xr[k] * values[(int)w[k]];
  }
  out[(size_t)t * OF + o] = sum + bias[o];
}

extern "C" void kernel_launch(void* const* d_in, const int* in_sizes, int n_in,
                              void* d_out, int out_size, void* d_ws, size_t ws_size,
                              hipStream_t stream) {
  const float* x      = (const float*)d_in[0];
  const float* values = (const float*)d_in[1];
  const int*   widx   = (const int*)d_in[2];
  const float* bias   = (const float*)d_in[3];
  float* out = (float*)d_out;

  const long xsz = in_sizes[0];
  const int  OF  = in_sizes[3];
  const long wsz = in_sizes[2];
  const int  IF  = (int)(wsz / OF);
  const int  NTOK = (int)(xsz / IF);

  u16* xb = (u16*)d_ws;
  u16* wb = xb + (size_t)NTOK * IF;
  int* flag = (int*)(wb + (size_t)OF * IF);
  const size_t need = ((size_t)NTOK * IF + (size_t)OF * IF) * sizeof(u16) + 64;

  const bool pre_ok = (ws_size >= need) && ((xsz % 8) == 0) && ((wsz % 4) == 0);
  const bool f256 = pre_ok && (IF % 128 == 0) && (IF >= 256) &&
                    (NTOK % 256 == 0) && (OF % 256 == 0);
  const bool f128 = pre_ok && (IF % 32 == 0) && (NTOK % 128 == 0) && (OF % 128 == 0);

  if (f256 || f128) {
    hipLaunchKernelGGL(detect_idx_width, dim3(1), dim3(64), 0, stream,
                       (const unsigned*)widx, flag);
    hipLaunchKernelGGL(prepass_kernel, dim3(2048), dim3(256), 0, stream,
                       (const float4*)x, xb, xsz / 8,
                       (const int4*)widx, values, wb, (const int*)flag, wsz / 4);
    if (f256) {
      const int grid = (NTOK / 256) * (OF / 256);
      hipLaunchKernelGGL(gemm256_kernel, dim3(grid), dim3(512), 0, stream,
                         xb, wb, bias, out, OF, IF);
    } else {
      const int grid = (NTOK / 128) * (OF / 128);
      hipLaunchKernelGGL(gemm128_kernel, dim3(grid), dim3(256), 0, stream,
                         xb, wb, bias, out, OF, IF);
    }
  } else {
    int* flag2 = (int*)d_ws;
    hipLaunchKernelGGL(detect_idx_width, dim3(1), dim3(64), 0, stream,
                       (const unsigned*)widx, flag2);
    hipLaunchKernelGGL(fallback_kernel, dim3((OF + 255) / 256, NTOK), dim3(256), 0, stream,
                       x, values, widx, bias, out, (const int*)flag2, NTOK, IF, OF);
  }
}